// Round 2
// baseline (456.433 us; speedup 1.0000x reference)
//
#include <hip/hip_runtime.h>
#include <math.h>

#define EPSF 1e-10f

// ---------------------------------------------------------------------------
// Setup kernel: recompute the Lloyd-Max codebook (7-bit, unit Gaussian) in
// float64 exactly as the host reference does (200 iterations), then emit
//   ws[0..127]   : float32 codebook
//   ws[128..254] : float32 decision boundaries (midpoints of f32 codebook)
// Single block, 128 threads. Deterministic; runs every launch (no caching).
// ---------------------------------------------------------------------------
__global__ __launch_bounds__(128) void lloyd_setup_kernel(float* __restrict__ ws) {
    __shared__ double lv[128];
    __shared__ double bp[127];   // pdf at boundary i
    __shared__ double bc[127];   // cdf at boundary i

    const int i = threadIdx.x;   // 0..127
    // np.linspace(-4, 4, 128)
    lv[i] = (i == 127) ? 4.0 : (-4.0 + (8.0 / 127.0) * (double)i);
    __syncthreads();

    const double inv_sqrt2pi = 0.39894228040143267794;  // 1/sqrt(2*pi)
    const double inv_sqrt2   = 0.70710678118654752440;  // 1/sqrt(2)

    // endpoint values at +-30 (the reference clips to [-30, 30])
    const double pdf_end = exp(-0.5 * 30.0 * 30.0) * inv_sqrt2pi;
    const double cdf_m30 = 0.5 * (1.0 + erf(-30.0 * inv_sqrt2));
    const double cdf_p30 = 0.5 * (1.0 + erf( 30.0 * inv_sqrt2));

    for (int it = 0; it < 200; ++it) {
        if (i < 127) {
            double t = 0.5 * (lv[i] + lv[i + 1]);
            t = fmin(fmax(t, -30.0), 30.0);
            bp[i] = exp(-0.5 * t * t) * inv_sqrt2pi;
            bc[i] = 0.5 * (1.0 + erf(t * inv_sqrt2));
        }
        __syncthreads();
        const double plo = (i == 0)   ? pdf_end : bp[i - 1];
        const double clo = (i == 0)   ? cdf_m30 : bc[i - 1];
        const double phi = (i == 127) ? pdf_end : bp[i];
        const double chi = (i == 127) ? cdf_p30 : bc[i];
        const double nl  = (plo - phi) / fmax(chi - clo, 1e-30);
        __syncthreads();
        lv[i] = nl;
        __syncthreads();
    }

    // float32 codebook
    const float cf = (float)lv[i];
    ws[i] = cf;
    // boundaries from the FLOAT32 codebook (matches reference astype order)
    if (i < 127) {
        ws[128 + i] = 0.5f * (cf + (float)lv[i + 1]);
    }
}

// ---------------------------------------------------------------------------
// Main kernel: one wave64 per 128-element row; lane l holds elements 2l, 2l+1.
// ---------------------------------------------------------------------------

__device__ __forceinline__ float wave_sum64(float v) {
#pragma unroll
    for (int d = 1; d <= 32; d <<= 1) v += __shfl_xor(v, d, 64);
    return v;
}

// normalized FWHT over 128 elements held as (a,b)=(e[2l],e[2l+1]) across 64 lanes
__device__ __forceinline__ void fwht128(float& a, float& b, const int lane) {
    // stage h=1 (within lane)
    const float t0 = a + b;
    const float t1 = a - b;
    a = t0; b = t1;
    // stages h=2..64 -> lane-xor distances 1..32 (stages commute)
#pragma unroll
    for (int d = 1; d <= 32; d <<= 1) {
        const float pa = __shfl_xor(a, d, 64);
        const float pb = __shfl_xor(b, d, 64);
        const bool up = (lane & d) == 0;
        a = up ? (a + pa) : (pa - a);
        b = up ? (b + pb) : (pb - b);
    }
    const float s = 0.08838834764831845f;  // 1/sqrt(128)
    a *= s; b *= s;
}

// searchsorted(bounds, v, side='left') over 127 bounds (LDS array padded with +inf)
__device__ __forceinline__ int lower_bound127(const float* __restrict__ bnd, float v) {
    int idx = 0;
#pragma unroll
    for (int d = 64; d >= 1; d >>= 1) {
        idx += (bnd[idx + d - 1] < v) ? d : 0;
    }
    return idx;
}

__global__ __launch_bounds__(256) void turboquant_kernel(
        const float* __restrict__ x,
        const float* __restrict__ rot,    // [2][128]
        const float* __restrict__ qjl,    // [128]
        const float* __restrict__ ws,     // codebook/bounds from setup
        float* __restrict__ out,
        const int nrows) {
    __shared__ float cb[128];
    __shared__ float bnd[128];

    const int t = threadIdx.x;
    if (t < 128) {
        cb[t]  = ws[t];
        bnd[t] = (t < 127) ? ws[128 + t] : 3.402823466e38f;  // sentinel +inf
    }
    __syncthreads();

    const int lane = t & 63;
    const int wid  = t >> 6;

    // per-lane constants (elements 2l, 2l+1)
    const float rs0a = rot[2 * lane],       rs0b = rot[2 * lane + 1];
    const float rs1a = rot[128 + 2 * lane], rs1b = rot[128 + 2 * lane + 1];
    const float qja  = qjl[2 * lane],       qjb  = qjl[2 * lane + 1];

    const int waves_total = gridDim.x * 4;
    for (int row = blockIdx.x * 4 + wid; row < nrows; row += waves_total) {
        const float2 xin = ((const float2*)(x + (size_t)row * 128))[lane];
        float a = xin.x, b = xin.y;

        // ---- norms, unit vector ----
        const float n2   = wave_sum64(a * a + b * b);
        const float norm = sqrtf(n2);
        const float ninv = 1.0f / (norm + EPSF);
        a *= ninv; b *= ninv;

        // ---- rotation_fwd: (sign-flip then FWHT) x2 ----
        a *= rs0a; b *= rs0b; fwht128(a, b, lane);
        a *= rs1a; b *= rs1b; fwht128(a, b, lane);

        // ---- first pass: RMS scale + LM quantize ----
        const float rms = sqrtf(wave_sum64(a * a + b * b)) * 0.08838834764831845f;
        const float si  = 1.0f / (rms + EPSF);
        const float ra  = cb[lower_bound127(bnd, a * si)];
        const float rb  = cb[lower_bound127(bnd, b * si)];

        // ---- refined gamma ----
        const float num   = wave_sum64(a * ra + b * rb);
        const float den   = wave_sum64(ra * ra + rb * rb) + EPSF;
        const float gamma = num / den;

        // ---- MSE-stage quantize ----
        const float gi = 1.0f / (gamma + EPSF);
        const float ua = cb[lower_bound127(bnd, a * gi)];
        const float ub = cb[lower_bound127(bnd, b * gi)];
        const float recon_a = ua * gamma;
        const float recon_b = ub * gamma;

        // ---- residual + its norm ----
        const float res_a = a - recon_a;
        const float res_b = b - recon_b;
        const float res2  = wave_sum64(res_a * res_a + res_b * res_b);
        const float resn  = sqrtf(res2);   // ||residual|| (rotated domain)

        // ---- QJL 1-bit sketch ----
        float pa = res_a * qja, pb = res_b * qjb;
        fwht128(pa, pb, lane);
        float sa = (pa >= 0.0f) ? 1.0f : -1.0f;
        float sb = (pb >= 0.0f) ? 1.0f : -1.0f;

        // ---- dequantize: direction from sign bits ----
        fwht128(sa, sb, lane);
        const float da = sa * qja, db = sb * qjb;
        const float dn = sqrtf(wave_sum64(da * da + db * db)) + EPSF;

        // unit_res = (resn * norm) / (norm + EPS)
        const float unit_res = resn * norm / (norm + EPSF);
        const float rscale   = unit_res / dn;

        float ca = recon_a + da * rscale;
        float cbv = recon_b + db * rscale;

        // ---- rotation_inv: (FWHT then sign-flip), p = 1 then 0 ----
        fwht128(ca, cbv, lane);
        ca *= rs1a; cbv *= rs1b;
        fwht128(ca, cbv, lane);
        ca *= rs0a; cbv *= rs0b;

        // ---- scale back by norm, store ----
        float2 o;
        o.x = ca  * norm;
        o.y = cbv * norm;
        ((float2*)(out + (size_t)row * 128))[lane] = o;
    }
}

extern "C" void kernel_launch(void* const* d_in, const int* in_sizes, int n_in,
                              void* d_out, int out_size, void* d_ws, size_t ws_size,
                              hipStream_t stream) {
    const float* x   = (const float*)d_in[0];
    const float* rot = (const float*)d_in[1];
    const float* qjl = (const float*)d_in[2];
    float* out = (float*)d_out;
    float* ws  = (float*)d_ws;

    const int nrows = in_sizes[0] >> 7;  // 128 elements per row

    lloyd_setup_kernel<<<1, 128, 0, stream>>>(ws);

    const int blocks = 8192;  // 4 waves/block, grid-stride over rows
    turboquant_kernel<<<blocks, 256, 0, stream>>>(x, rot, qjl, ws, out, nrows);
}

// Round 5
// 268.892 us; speedup vs baseline: 1.6975x; 1.6975x over previous
//
#include <hip/hip_runtime.h>
#include <math.h>

#define EPSF 1e-10f
#define INV128 0.0078125f
#define C128 0.08838834764831845f   // np.float32(1/sqrt(128))

// ---------------- cross-lane primitives ------------------------------------

template<int CTRL>
__device__ __forceinline__ float fdpp(float v) {
    return __builtin_bit_cast(float,
        __builtin_amdgcn_update_dpp(0, __builtin_bit_cast(int, v), CTRL, 0xF, 0xF, true));
}
template<int PAT>
__device__ __forceinline__ float fswz(float v) {
    return __builtin_bit_cast(float,
        __builtin_amdgcn_ds_swizzle(__builtin_bit_cast(int, v), PAT));
}
__device__ __forceinline__ float pl32(float v, bool lower) {
#if __has_builtin(__builtin_amdgcn_permlane32_swap)
    auto r = __builtin_amdgcn_permlane32_swap(
        __builtin_bit_cast(unsigned, v), __builtin_bit_cast(unsigned, v), false, false);
    return __builtin_bit_cast(float, lower ? r[1] : r[0]);
#else
    return __shfl_xor(v, 32, 64);
#endif
}

// partner value at lane^D; DPP=false uses __shfl_xor (round-1-proven path)
template<bool DPP, int D>
__device__ __forceinline__ float partner(float v, bool lower) {
    if constexpr (!DPP)        { return __shfl_xor(v, D, 64); }
    else if constexpr (D == 1) { return fdpp<0xB1>(v); }     // quad_perm xor1
    else if constexpr (D == 2) { return fdpp<0x4E>(v); }     // quad_perm xor2
    else if constexpr (D == 4) { return fswz<0x101F>(v); }   // ds_swizzle xor4
    else if constexpr (D == 8) { return fdpp<0x128>(v); }    // row_ror:8 == xor8
    else if constexpr (D == 16){ return fswz<0x401F>(v); }   // ds_swizzle xor16
    else                       { return pl32(v, lower); }
}

template<bool DPP>
__device__ __forceinline__ float wave_sum64(float v, bool lower) {
    v += partner<DPP, 1>(v, lower);
    v += partner<DPP, 2>(v, lower);
    v += partner<DPP, 4>(v, lower);
    v += partner<DPP, 8>(v, lower);
    v += partner<DPP, 16>(v, lower);
    v += partner<DPP, 32>(v, lower);
    return v;
}

struct Signs { float s1, s2, s4, s8, s16, s32; bool lower; };

// FWHT over 128 elems; lane l holds (e[2l], e[2l+1]). fmaf(+-1, a, p) is
// bitwise identical to (a+p)/(p-a). SCALE applies the reference's per-call
// *float32(1/sqrt(128)) at the end (quantizer-feeding calls need it).
template<bool DPP, bool SCALE>
__device__ __forceinline__ void fwht128(float& a, float& b, const Signs& S) {
    float t0 = a + b, t1 = a - b; a = t0; b = t1;          // dist 1 (in-lane)
    a = fmaf(S.s1,  a, partner<DPP, 1>(a, S.lower));  b = fmaf(S.s1,  b, partner<DPP, 1>(b, S.lower));
    a = fmaf(S.s2,  a, partner<DPP, 2>(a, S.lower));  b = fmaf(S.s2,  b, partner<DPP, 2>(b, S.lower));
    a = fmaf(S.s4,  a, partner<DPP, 4>(a, S.lower));  b = fmaf(S.s4,  b, partner<DPP, 4>(b, S.lower));
    a = fmaf(S.s8,  a, partner<DPP, 8>(a, S.lower));  b = fmaf(S.s8,  b, partner<DPP, 8>(b, S.lower));
    a = fmaf(S.s16, a, partner<DPP, 16>(a, S.lower)); b = fmaf(S.s16, b, partner<DPP, 16>(b, S.lower));
    float pa = partner<DPP, 32>(a, S.lower), pb = partner<DPP, 32>(b, S.lower);
    a = fmaf(S.s32, a, pa); b = fmaf(S.s32, b, pb);
    if constexpr (SCALE) { a *= C128; b *= C128; }
}

// Self-check: verify every DPP primitive bitwise against __shfl_xor on a
// distinguishing pattern. Wave-uniform verdict.
__device__ __forceinline__ bool dpp_ok(int lane) {
    const bool lower = (lane & 32) == 0;
    const float tv = __int_as_float(0x3f800000 + lane * 1024);  // 64 distinct
    bool ok = true;
    ok = ok && (__float_as_uint(partner<true, 1>(tv, lower)) == __float_as_uint(__shfl_xor(tv, 1, 64)));
    ok = ok && (__float_as_uint(partner<true, 2>(tv, lower)) == __float_as_uint(__shfl_xor(tv, 2, 64)));
    ok = ok && (__float_as_uint(partner<true, 4>(tv, lower)) == __float_as_uint(__shfl_xor(tv, 4, 64)));
    ok = ok && (__float_as_uint(partner<true, 8>(tv, lower)) == __float_as_uint(__shfl_xor(tv, 8, 64)));
    ok = ok && (__float_as_uint(partner<true, 16>(tv, lower)) == __float_as_uint(__shfl_xor(tv, 16, 64)));
    ok = ok && (__float_as_uint(partner<true, 32>(tv, lower)) == __float_as_uint(__shfl_xor(tv, 32, 64)));
    return __all((int)ok) != 0;
}

// ---------------------------------------------------------------------------
// Setup: round-1 verbatim Lloyd-Max (128 threads, f64 shared) + LUT/tbl build.
// ws layout (floats): [0..127] cb | [128..255] bnd (+inf at 255) |
//                     [256..767] float4 tbl[128]{bnd,cb,cb_next,0} |
//                     [768..1791] int lut[1024]
// ---------------------------------------------------------------------------
__global__ __launch_bounds__(128) void lloyd_setup_kernel(float* __restrict__ ws) {
    __shared__ double lv[128];
    __shared__ double bp[127];
    __shared__ double bc[127];
    __shared__ float scb[128];
    __shared__ float sbnd[128];

    const int i = threadIdx.x;   // 0..127
    lv[i] = (i == 127) ? 4.0 : (-4.0 + (8.0 / 127.0) * (double)i);
    __syncthreads();

    const double inv_sqrt2pi = 0.39894228040143267794;
    const double inv_sqrt2   = 0.70710678118654752440;
    const double pdf_end = exp(-0.5 * 30.0 * 30.0) * inv_sqrt2pi;
    const double cdf_m30 = 0.5 * (1.0 + erf(-30.0 * inv_sqrt2));
    const double cdf_p30 = 0.5 * (1.0 + erf( 30.0 * inv_sqrt2));

    for (int it = 0; it < 200; ++it) {
        if (i < 127) {
            double t = 0.5 * (lv[i] + lv[i + 1]);
            t = fmin(fmax(t, -30.0), 30.0);
            bp[i] = exp(-0.5 * t * t) * inv_sqrt2pi;
            bc[i] = 0.5 * (1.0 + erf(t * inv_sqrt2));
        }
        __syncthreads();
        const double plo = (i == 0)   ? pdf_end : bp[i - 1];
        const double clo = (i == 0)   ? cdf_m30 : bc[i - 1];
        const double phi = (i == 127) ? pdf_end : bp[i];
        const double chi = (i == 127) ? cdf_p30 : bc[i];
        const double nl  = (plo - phi) / fmax(chi - clo, 1e-30);
        __syncthreads();
        lv[i] = nl;
        __syncthreads();
    }

    const float cf = (float)lv[i];
    ws[i] = cf;
    scb[i] = cf;
    __syncthreads();

    const float INF = __int_as_float(0x7f800000);
    const float nb = (i < 127) ? 0.5f * (scb[i] + scb[i + 1]) : INF;
    ws[128 + i] = nb;
    sbnd[i] = nb;

    float4* tbl = (float4*)(ws + 256);
    tbl[i] = make_float4(nb, scb[i], scb[(i < 127) ? i + 1 : 127], 0.0f);
    __syncthreads();

    int* lut = (int*)(ws + 768);
    for (int c = i; c < 1024; c += 128) {
        const float cl = -4.0f + (float)c * 0.0078125f;   // cell left edge
        int g = 0;
#pragma unroll
        for (int d = 64; d >= 1; d >>= 1) g += (sbnd[g + d - 1] < cl) ? d : 0;
        lut[c] = g;   // #bounds < cell_left; true idx in {g, g+1}
    }
}

// ---------------------------------------------------------------------------
// Main kernel
// ---------------------------------------------------------------------------
// Exactly equivalent to lower_bound over bnd (min boundary gap 0.034 > cell
// width 1/128 => at most one boundary in [cell_left, v]).
__device__ __forceinline__ float lm_recon(const float4* __restrict__ tbl,
                                          const int* __restrict__ lut, float v) {
    float cf = fminf(fmaxf(fmaf(v, 128.0f, 512.0f), 0.0f), 1023.0f);
    int g = lut[(int)cf];
    float4 e = tbl[g];
    return (e.x < v) ? e.z : e.y;   // searchsorted side='left'
}

template<bool DPP>
__device__ __forceinline__ void run_rows(
        const float* __restrict__ x, float* __restrict__ out,
        const float4* __restrict__ tbl, const int* __restrict__ lut,
        float rs0a, float rs0b, float rs1a, float rs1b, float qja, float qjb,
        const Signs S, int lane, int row0, int wstride, int nrows) {
    for (int row = row0; row < nrows; row += wstride) {
        const float2 xin = ((const float2*)(x + (size_t)row * 128))[lane];
        float a = xin.x, b = xin.y;

        // ---- norm, unit vector (round-1 exact arithmetic) ----
        const float norm = sqrtf(wave_sum64<DPP>(a * a + b * b, S.lower));
        const float ninv = 1.0f / (norm + EPSF);
        a *= ninv; b *= ninv;

        // ---- rotation_fwd, per-FWHT normalized (feeds quantizer) ----
        a *= rs0a; b *= rs0b;
        fwht128<DPP, true>(a, b, S);
        a *= rs1a; b *= rs1b;
        fwht128<DPP, true>(a, b, S);

        // ---- pass 1: numerical rms + LM quantize ----
        const float rms = sqrtf(wave_sum64<DPP>(a * a + b * b, S.lower)) * C128;
        const float si  = 1.0f / (rms + EPSF);
        const float ra  = lm_recon(tbl, lut, a * si);
        const float rb  = lm_recon(tbl, lut, b * si);

        // ---- refined gamma ----
        const float num   = wave_sum64<DPP>(a * ra + b * rb, S.lower);
        const float den   = wave_sum64<DPP>(ra * ra + rb * rb, S.lower) + EPSF;
        const float gamma = num / den;
        const float gi    = 1.0f / (gamma + EPSF);

        // ---- MSE-stage quantize ----
        const float ua = lm_recon(tbl, lut, a * gi);
        const float ub = lm_recon(tbl, lut, b * gi);
        const float rca = ua * gamma, rcb = ub * gamma;
        const float resa = a - rca, resb = b - rcb;
        const float resn = sqrtf(wave_sum64<DPP>(resa * resa + resb * resb, S.lower));

        // ==== everything below is post-quantization (ulp-safe folds) ====
        // QJL sketch: sign of unscaled projection == sign of scaled
        float pa = resa * qja, pb = resb * qjb;
        fwht128<DPP, false>(pa, pb, S);
        float sa  = (pa >= 0.0f) ? 1.0f : -1.0f;
        float sbv = (pb >= 0.0f) ? 1.0f : -1.0f;

        // direction: raw FWHT of +-1 is exact integers; norms fold to resn/128
        fwht128<DPP, false>(sa, sbv, S);
        const float rscale = resn * INV128;
        float ca = fmaf(sa * qja,  rscale, rca);
        float cb = fmaf(sbv * qjb, rscale, rcb);

        // inverse rotation with folded scales
        fwht128<DPP, false>(ca, cb, S);
        ca *= rs1a; cb *= rs1b;
        fwht128<DPP, false>(ca, cb, S);
        const float fn = norm * INV128;
        float2 o;
        o.x = ca * rs0a * fn;
        o.y = cb * rs0b * fn;
        ((float2*)(out + (size_t)row * 128))[lane] = o;
    }
}

__global__ __launch_bounds__(256) void turboquant_kernel(
        const float* __restrict__ x,
        const float* __restrict__ rot,
        const float* __restrict__ qjl,
        const float* __restrict__ ws,
        float* __restrict__ out,
        const int nrows) {
    __shared__ float4 tbl[128];
    __shared__ int lut[1024];

    const int t = threadIdx.x;
    if (t < 128) tbl[t] = ((const float4*)(ws + 256))[t];
    {
        const int* lsrc = (const int*)(ws + 768);
#pragma unroll
        for (int i = 0; i < 4; ++i) lut[t + 256 * i] = lsrc[t + 256 * i];
    }
    __syncthreads();

    const int lane = t & 63;
    const int wid  = t >> 6;

    Signs S;
    S.s1  = (lane & 1)  ? -1.0f : 1.0f;
    S.s2  = (lane & 2)  ? -1.0f : 1.0f;
    S.s4  = (lane & 4)  ? -1.0f : 1.0f;
    S.s8  = (lane & 8)  ? -1.0f : 1.0f;
    S.s16 = (lane & 16) ? -1.0f : 1.0f;
    S.s32 = (lane & 32) ? -1.0f : 1.0f;
    S.lower = (lane & 32) == 0;

    const float rs0a = rot[2 * lane],       rs0b = rot[2 * lane + 1];
    const float rs1a = rot[128 + 2 * lane], rs1b = rot[128 + 2 * lane + 1];
    const float qja  = qjl[2 * lane],       qjb  = qjl[2 * lane + 1];

    const int row0    = blockIdx.x * 4 + wid;
    const int wstride = gridDim.x * 4;

    if (dpp_ok(lane)) {
        run_rows<true >(x, out, tbl, lut, rs0a, rs0b, rs1a, rs1b, qja, qjb,
                        S, lane, row0, wstride, nrows);
    } else {
        run_rows<false>(x, out, tbl, lut, rs0a, rs0b, rs1a, rs1b, qja, qjb,
                        S, lane, row0, wstride, nrows);
    }
}

extern "C" void kernel_launch(void* const* d_in, const int* in_sizes, int n_in,
                              void* d_out, int out_size, void* d_ws, size_t ws_size,
                              hipStream_t stream) {
    const float* x   = (const float*)d_in[0];
    const float* rot = (const float*)d_in[1];
    const float* qjl = (const float*)d_in[2];
    float* out = (float*)d_out;
    float* ws  = (float*)d_ws;

    const int nrows = in_sizes[0] >> 7;

    lloyd_setup_kernel<<<1, 128, 0, stream>>>(ws);
    turboquant_kernel<<<8192, 256, 0, stream>>>(x, rot, qjl, ws, out, nrows);
}